// Round 5
// baseline (429.067 us; speedup 1.0000x reference)
//
#include <hip/hip_runtime.h>

#define N_NODES 50000
#define HIDDEN 128
#define NBUCK ((N_NODES + 127) >> 7)  // 391 coarse buckets of 128 dst nodes

typedef __attribute__((ext_vector_type(8))) short short8;
typedef __attribute__((ext_vector_type(4))) float f32x4;

__device__ __forceinline__ unsigned short f2bf(float f) {
    union { float f; unsigned int u; } a; a.f = f;
    unsigned int u = a.u;
    u += 0x7FFFu + ((u >> 16) & 1u);  // RNE
    return (unsigned short)(u >> 16);
}
__device__ __forceinline__ float bf2f(unsigned int bits16) {
    union { unsigned int u; float f; } a; a.u = bits16 << 16;
    return a.f;
}

// Pack Wcat[256][128] (rows 0..127 = Wl^T, 128..255 = Wr^T) into MFMA-B
// fragment order: Wp[((ks*8+nf)*64+lane)*8+j] = Wcat[ks*32+(lane>>4)*8+j][nf*16+(lane&15)]
__global__ void pack_w(const float* __restrict__ Wl, const float* __restrict__ Wr,
                       unsigned short* __restrict__ Wp) {
    int tid = blockIdx.x * blockDim.x + threadIdx.x;  // 32768
    int j = tid & 7, lane = (tid >> 3) & 63, nf = (tid >> 9) & 7, ks = tid >> 12;
    int k = ks * 32 + ((lane >> 4) * 8) + j;
    int t = nf * 16 + (lane & 15);
    float v = (k < 128) ? Wl[t * 128 + k] : Wr[t * 128 + (k - 128)];
    Wp[tid] = f2bf(v);
}

__global__ void cast_bf16(const float* __restrict__ x, unsigned short* __restrict__ xb, int n4) {
    int i = blockIdx.x * blockDim.x + threadIdx.x;
    if (i >= n4) return;
    float4 v = reinterpret_cast<const float4*>(x)[i];
    ushort4 o = make_ushort4(f2bf(v.x), f2bf(v.y), f2bf(v.z), f2bf(v.w));
    reinterpret_cast<ushort4*>(xb)[i] = o;
}

// ---- CSR build, two-level counting sort ----

// Coarse histogram: LDS per-block hist, then one global add per (block,bucket).
__global__ __launch_bounds__(1024) void bucket_hist(const int* __restrict__ dst, int E,
                                                    int* __restrict__ bcnt) {
    __shared__ int h[NBUCK];
    for (int i = threadIdx.x; i < NBUCK; i += 1024) h[i] = 0;
    __syncthreads();
    for (int e = blockIdx.x * 1024 + threadIdx.x; e < E; e += gridDim.x * 1024)
        atomicAdd(&h[dst[e] >> 7], 1);
    __syncthreads();
    for (int i = threadIdx.x; i < NBUCK; i += 1024)
        if (h[i]) atomicAdd(&bcnt[i], h[i]);
}

// Exclusive scan of 391 bucket counts (single block); writes boff[0..NBUCK] and bcur.
__global__ __launch_bounds__(512) void scan_buckets(const int* __restrict__ bcnt,
                                                    int* __restrict__ boff,
                                                    int* __restrict__ bcur) {
    __shared__ int ws[8];
    const int tid = threadIdx.x, lane = tid & 63, wid = tid >> 6;
    const int v = (tid < NBUCK) ? bcnt[tid] : 0;
    int incl = v;
#pragma unroll
    for (int off = 1; off < 64; off <<= 1) {
        int t = __shfl_up(incl, off);
        if (lane >= off) incl += t;
    }
    if (lane == 63) ws[wid] = incl;
    __syncthreads();
    if (wid == 0) {
        int wv = (lane < 8) ? ws[lane] : 0;
        int wincl = wv;
#pragma unroll
        for (int off = 1; off < 8; off <<= 1) {
            int t = __shfl_up(wincl, off);
            if (lane >= off) wincl += t;
        }
        if (lane < 8) ws[lane] = wincl - wv;
    }
    __syncthreads();
    const int excl = ws[wid] + incl - v;
    if (tid < NBUCK) { boff[tid] = excl; bcur[tid] = excl; }
    if (tid == NBUCK - 1) boff[NBUCK] = excl + v;
}

// Scatter packed (dst<<16)|src into per-bucket sequential streams.
__global__ void partition_edges(const int* __restrict__ src, const int* __restrict__ dst,
                                int E, int* __restrict__ bcur,
                                unsigned int* __restrict__ packed) {
    int e = blockIdx.x * blockDim.x + threadIdx.x;
    if (e < E) {
        int d = dst[e];
        int p = atomicAdd(&bcur[d >> 7], 1);
        packed[p] = ((unsigned int)d << 16) | (unsigned int)src[e];
    }
}

// One block per bucket: LDS 128-bin hist + scan -> row_start; LDS-cursor scatter
// of u16 srcs into the bucket's contiguous ~8KB output region.
__global__ __launch_bounds__(256) void build_rows(const unsigned int* __restrict__ packed,
                                                  const int* __restrict__ boff,
                                                  int* __restrict__ row_start,
                                                  unsigned short* __restrict__ ssrc) {
    __shared__ int lh[128];
    __shared__ int lc[128];
    __shared__ int htot;
    const int b = blockIdx.x;
    const int gbase = boff[b], gend = boff[b + 1];
    const int tid = threadIdx.x;
    if (tid < 128) lh[tid] = 0;
    __syncthreads();
    for (int i = gbase + tid; i < gend; i += 256)
        atomicAdd(&lh[(packed[i] >> 16) & 127], 1);
    __syncthreads();
    int v = 0, incl = 0;
    if (tid < 128) {
        const int lane = tid & 63;
        v = lh[tid];
        incl = v;
#pragma unroll
        for (int off = 1; off < 64; off <<= 1) {
            int t = __shfl_up(incl, off);
            if (lane >= off) incl += t;
        }
        if (tid == 63) htot = incl;
    }
    __syncthreads();
    if (tid < 128) {
        const int excl = incl - v + ((tid >= 64) ? htot : 0);
        lc[tid] = gbase + excl;
        const int node = b * 128 + tid;
        if (node <= N_NODES) row_start[node] = gbase + excl;
    }
    __syncthreads();
    for (int i = gbase + tid; i < gend; i += 256) {
        const unsigned int p = packed[i];
        const int pos = atomicAdd(&lc[(p >> 16) & 127], 1);
        ssrc[pos] = (unsigned short)(p & 0xffffu);
    }
}

// 32 lanes per node (lane owns 4 features via ushort4), 2 nodes per wave,
// unroll 4 -> 8 row-gathers in flight per wave.
__global__ __launch_bounds__(256) void aggregate_mean_bf16(
    const unsigned short* __restrict__ featb, const int* __restrict__ row_start,
    const unsigned short* __restrict__ ssrc, unsigned short* __restrict__ aggb) {
    const int node = blockIdx.x * 8 + (threadIdx.x >> 5);
    const int l = threadIdx.x & 31;
    if (node >= N_NODES) return;
    const int beg = row_start[node], end = row_start[node + 1];
    float acc[4][4];
#pragma unroll
    for (int u = 0; u < 4; ++u)
#pragma unroll
        for (int f = 0; f < 4; ++f) acc[u][f] = 0.f;

    int j = beg;
    for (; j + 3 < end; j += 4) {
#pragma unroll
        for (int u = 0; u < 4; ++u) {
            const int s = ssrc[j + u];
            const ushort4 v = *reinterpret_cast<const ushort4*>(&featb[(size_t)s * HIDDEN + 4 * l]);
            acc[u][0] += bf2f(v.x); acc[u][1] += bf2f(v.y);
            acc[u][2] += bf2f(v.z); acc[u][3] += bf2f(v.w);
        }
    }
    for (; j < end; ++j) {
        const int s = ssrc[j];
        const ushort4 v = *reinterpret_cast<const ushort4*>(&featb[(size_t)s * HIDDEN + 4 * l]);
        acc[0][0] += bf2f(v.x); acc[0][1] += bf2f(v.y);
        acc[0][2] += bf2f(v.z); acc[0][3] += bf2f(v.w);
    }
    const int d = end - beg;
    const float inv = d ? 1.0f / (float)d : 0.0f;
    ushort4 o;
    o.x = f2bf((acc[0][0] + acc[1][0] + acc[2][0] + acc[3][0]) * inv);
    o.y = f2bf((acc[0][1] + acc[1][1] + acc[2][1] + acc[3][1]) * inv);
    o.z = f2bf((acc[0][2] + acc[1][2] + acc[2][2] + acc[3][2]) * inv);
    o.w = f2bf((acc[0][3] + acc[1][3] + acc[2][3] + acc[3][3]) * inv);
    *reinterpret_cast<ushort4*>(&aggb[(size_t)node * HIDDEN + 4 * l]) = o;
}

// out[n][t] = relu?( sum_k aggb[n][k]*Wl[t][k] + xb[n][k]*Wr[t][k] + b[t] )
// 4 waves/block (2M x 2N), 64-row x 128-col tile, K=256 in 8 steps of 32.
// Layer 1 (WRITE_BF16_RELU=1) writes bf16 IN-PLACE over xb: each block reads
// only its own 64 rows (k-loop) before its epilogue stores -> no hazard.
template <int WRITE_BF16_RELU>
__global__ __launch_bounds__(256) void mfma_linear(
    const unsigned short* aggb, const unsigned short* xb,
    const unsigned short* __restrict__ Wp, const float* __restrict__ bias,
    unsigned short* out_b, float* out_f) {
    const int lane = threadIdx.x & 63;
    const int wave = threadIdx.x >> 6;
    const int wm = wave >> 1, wn = wave & 1;
    const int rowbase = blockIdx.x * 64 + wm * 32;
    const int colbase = wn * 64;
    const int l15 = lane & 15, l4 = lane >> 4;

    f32x4 acc[2][4];
#pragma unroll
    for (int m = 0; m < 2; ++m)
#pragma unroll
        for (int nf = 0; nf < 4; ++nf) acc[m][nf] = (f32x4){0.f, 0.f, 0.f, 0.f};

#pragma unroll
    for (int ks = 0; ks < 8; ++ks) {
        const unsigned short* Asrc = (ks < 4) ? aggb : xb;
        const int koff = (ks & 3) * 32 + l4 * 8;
        short8 a[2];
#pragma unroll
        for (int m = 0; m < 2; ++m) {
            int row = rowbase + m * 16 + l15;
            if (row >= N_NODES) row = N_NODES - 1;
            a[m] = *reinterpret_cast<const short8*>(&Asrc[(size_t)row * HIDDEN + koff]);
        }
#pragma unroll
        for (int nf = 0; nf < 4; ++nf) {
            const int nfg = (colbase >> 4) + nf;
            short8 b = *reinterpret_cast<const short8*>(&Wp[(((size_t)ks * 8 + nfg) * 64 + lane) * 8]);
            acc[0][nf] = __builtin_amdgcn_mfma_f32_16x16x32_bf16(a[0], b, acc[0][nf], 0, 0, 0);
            acc[1][nf] = __builtin_amdgcn_mfma_f32_16x16x32_bf16(a[1], b, acc[1][nf], 0, 0, 0);
        }
    }

#pragma unroll
    for (int nf = 0; nf < 4; ++nf) {
        const int col = colbase + nf * 16 + l15;
        const float bv = bias[col];
#pragma unroll
        for (int m = 0; m < 2; ++m) {
#pragma unroll
            for (int r = 0; r < 4; ++r) {
                const int row = rowbase + m * 16 + l4 * 4 + r;
                if (row < N_NODES) {
                    float v = acc[m][nf][r] + bv;
                    if (WRITE_BF16_RELU) {
                        v = fmaxf(v, 0.0f);
                        out_b[(size_t)row * HIDDEN + col] = f2bf(v);
                    } else {
                        out_f[(size_t)row * HIDDEN + col] = v;
                    }
                }
            }
        }
    }
}

extern "C" void kernel_launch(void* const* d_in, const int* in_sizes, int n_in,
                              void* d_out, int out_size, void* d_ws, size_t ws_size,
                              hipStream_t stream) {
    const float* x   = (const float*)d_in[0];
    const int*   ei  = (const int*)d_in[1];
    const float* W1l = (const float*)d_in[2];
    const float* b1  = (const float*)d_in[3];
    const float* W1r = (const float*)d_in[4];
    const float* W2l = (const float*)d_in[5];
    const float* b2  = (const float*)d_in[6];
    const float* W2r = (const float*)d_in[7];

    const int E = in_sizes[1] / 2;
    const int* src = ei;
    const int* dst = ei + E;

    // ---- workspace layout (all sections 16B aligned) ----
    int* iws        = (int*)d_ws;
    int* bcnt       = iws;                       // @0    391 (pad 400)
    int* boff       = iws + 400;                 // @400  392 (pad 400)
    int* bcur       = iws + 800;                 // @800  391 (pad 400)
    int* row_start  = iws + 1200;                // @1200 50001 (pad 50004)
    unsigned int* packed = (unsigned int*)(iws + 51204);       // E u32
    unsigned short* ssrc = (unsigned short*)(iws + 51204 + E); // E u16 (E%8==0 keeps align)
    unsigned short* xb   = ssrc + E;             // 6.4M bf16 (h overwrites in-place)
    unsigned short* aggb = xb + (size_t)N_NODES * HIDDEN;      // 6.4M bf16
    unsigned short* Wp1  = aggb + (size_t)N_NODES * HIDDEN;    // 32768 bf16
    unsigned short* Wp2  = Wp1 + 256 * HIDDEN;                 // 32768 bf16

    hipMemsetAsync(bcnt, 0, NBUCK * sizeof(int), stream);

    pack_w<<<128, 256, 0, stream>>>(W1l, W1r, Wp1);
    pack_w<<<128, 256, 0, stream>>>(W2l, W2r, Wp2);
    cast_bf16<<<(N_NODES * HIDDEN / 4 + 255) / 256, 256, 0, stream>>>(x, xb, N_NODES * HIDDEN / 4);

    // ---- CSR build (shared by both layers) ----
    bucket_hist<<<196, 1024, 0, stream>>>(dst, E, bcnt);
    scan_buckets<<<1, 512, 0, stream>>>(bcnt, boff, bcur);
    partition_edges<<<(E + 255) / 256, 256, 0, stream>>>(src, dst, E, bcur, packed);
    build_rows<<<NBUCK, 256, 0, stream>>>(packed, boff, row_start, ssrc);

    const int aggGrid = (N_NODES + 7) / 8;
    const int linGrid = (N_NODES + 63) / 64;

    // ---- layer 1 ----
    aggregate_mean_bf16<<<aggGrid, 256, 0, stream>>>(xb, row_start, ssrc, aggb);
    mfma_linear<1><<<linGrid, 256, 0, stream>>>(aggb, xb, Wp1, b1, xb, nullptr);

    // ---- layer 2 ----
    aggregate_mean_bf16<<<aggGrid, 256, 0, stream>>>(xb, row_start, ssrc, aggb);
    mfma_linear<0><<<linGrid, 256, 0, stream>>>(aggb, xb, Wp2, b2, nullptr, (float*)d_out);
}

// Round 6
// 158.480 us; speedup vs baseline: 2.7074x; 2.7074x over previous
//
#include <hip/hip_runtime.h>

#define N_NODES 50000
#define HIDDEN 128
#define NBUCK ((N_NODES + 127) >> 7)  // 391 coarse buckets of 128 dst nodes

typedef __attribute__((ext_vector_type(8))) short short8;
typedef __attribute__((ext_vector_type(4))) float f32x4;

__device__ __forceinline__ unsigned short f2bf(float f) {
    union { float f; unsigned int u; } a; a.f = f;
    unsigned int u = a.u;
    u += 0x7FFFu + ((u >> 16) & 1u);  // RNE
    return (unsigned short)(u >> 16);
}
__device__ __forceinline__ float bf2f(unsigned int bits16) {
    union { unsigned int u; float f; } a; a.u = bits16 << 16;
    return a.f;
}

// Pack Wcat[256][128] (rows 0..127 = Wl^T, 128..255 = Wr^T) into MFMA-B
// fragment order: Wp[((ks*8+nf)*64+lane)*8+j] = Wcat[ks*32+(lane>>4)*8+j][nf*16+(lane&15)]
__global__ void pack_w(const float* __restrict__ Wl, const float* __restrict__ Wr,
                       unsigned short* __restrict__ Wp) {
    int tid = blockIdx.x * blockDim.x + threadIdx.x;  // 32768
    int j = tid & 7, lane = (tid >> 3) & 63, nf = (tid >> 9) & 7, ks = tid >> 12;
    int k = ks * 32 + ((lane >> 4) * 8) + j;
    int t = nf * 16 + (lane & 15);
    float v = (k < 128) ? Wl[t * 128 + k] : Wr[t * 128 + (k - 128)];
    Wp[tid] = f2bf(v);
}

__global__ void cast_bf16(const float* __restrict__ x, unsigned short* __restrict__ xb, int n4) {
    int i = blockIdx.x * blockDim.x + threadIdx.x;
    if (i >= n4) return;
    float4 v = reinterpret_cast<const float4*>(x)[i];
    ushort4 o = make_ushort4(f2bf(v.x), f2bf(v.y), f2bf(v.z), f2bf(v.w));
    reinterpret_cast<ushort4*>(xb)[i] = o;
}

// ---- CSR build, two-level counting sort ----

// Coarse histogram: LDS per-block hist, then one global add per (block,bucket).
__global__ __launch_bounds__(1024) void bucket_hist(const int* __restrict__ dst, int E,
                                                    int* __restrict__ bcnt) {
    __shared__ int h[NBUCK];
    for (int i = threadIdx.x; i < NBUCK; i += 1024) h[i] = 0;
    __syncthreads();
    for (int e = blockIdx.x * 1024 + threadIdx.x; e < E; e += gridDim.x * 1024)
        atomicAdd(&h[dst[e] >> 7], 1);
    __syncthreads();
    for (int i = threadIdx.x; i < NBUCK; i += 1024)
        if (h[i]) atomicAdd(&bcnt[i], h[i]);
}

// Exclusive scan of 391 bucket counts (single block); writes boff[0..NBUCK] and bcur.
__global__ __launch_bounds__(512) void scan_buckets(const int* __restrict__ bcnt,
                                                    int* __restrict__ boff,
                                                    int* __restrict__ bcur) {
    __shared__ int ws[8];
    const int tid = threadIdx.x, lane = tid & 63, wid = tid >> 6;
    const int v = (tid < NBUCK) ? bcnt[tid] : 0;
    int incl = v;
#pragma unroll
    for (int off = 1; off < 64; off <<= 1) {
        int t = __shfl_up(incl, off);
        if (lane >= off) incl += t;
    }
    if (lane == 63) ws[wid] = incl;
    __syncthreads();
    if (wid == 0) {
        int wv = (lane < 8) ? ws[lane] : 0;
        int wincl = wv;
#pragma unroll
        for (int off = 1; off < 8; off <<= 1) {
            int t = __shfl_up(wincl, off);
            if (lane >= off) wincl += t;
        }
        if (lane < 8) ws[lane] = wincl - wv;
    }
    __syncthreads();
    const int excl = ws[wid] + incl - v;
    if (tid < NBUCK) { boff[tid] = excl; bcur[tid] = excl; }
    if (tid == NBUCK - 1) boff[NBUCK] = excl + v;
}

// Block-aggregated partition: each block reserves per-bucket ranges with ONE
// global atomic per (block,bucket), then scatters via LDS cursors.
#define PCHUNK 4096  // edges per block (1024 threads x 4)
__global__ __launch_bounds__(1024) void partition_edges(
    const int* __restrict__ src, const int* __restrict__ dst, int E,
    int* __restrict__ bcur, unsigned int* __restrict__ packed) {
    __shared__ int h[NBUCK];     // local hist, then local cursor
    __shared__ int base[NBUCK];  // reserved global base per bucket
    const int tid = threadIdx.x;
    const int c0 = blockIdx.x * PCHUNK;
    for (int i = tid; i < NBUCK; i += 1024) h[i] = 0;
    __syncthreads();

    unsigned int val[4];
    int bk[4];
#pragma unroll
    for (int u = 0; u < 4; ++u) {
        const int e = c0 + u * 1024 + tid;
        if (e < E) {
            const int d = dst[e];
            val[u] = ((unsigned int)d << 16) | (unsigned int)src[e];
            bk[u] = d >> 7;
            atomicAdd(&h[bk[u]], 1);
        } else {
            bk[u] = -1;
        }
    }
    __syncthreads();
    for (int i = tid; i < NBUCK; i += 1024) {
        base[i] = h[i] ? atomicAdd(&bcur[i], h[i]) : 0;
        h[i] = 0;  // reuse as local cursor
    }
    __syncthreads();
#pragma unroll
    for (int u = 0; u < 4; ++u) {
        if (bk[u] >= 0) {
            const int pos = base[bk[u]] + atomicAdd(&h[bk[u]], 1);
            packed[pos] = val[u];
        }
    }
}

// One block per bucket: LDS 128-bin hist + scan -> row_start; LDS-cursor scatter
// of u16 srcs into the bucket's contiguous ~4KB output region.
__global__ __launch_bounds__(256) void build_rows(const unsigned int* __restrict__ packed,
                                                  const int* __restrict__ boff,
                                                  int* __restrict__ row_start,
                                                  unsigned short* __restrict__ ssrc) {
    __shared__ int lh[128];
    __shared__ int lc[128];
    __shared__ int htot;
    const int b = blockIdx.x;
    const int gbase = boff[b], gend = boff[b + 1];
    const int tid = threadIdx.x;
    if (tid < 128) lh[tid] = 0;
    __syncthreads();
    for (int i = gbase + tid; i < gend; i += 256)
        atomicAdd(&lh[(packed[i] >> 16) & 127], 1);
    __syncthreads();
    int v = 0, incl = 0;
    if (tid < 128) {
        const int lane = tid & 63;
        v = lh[tid];
        incl = v;
#pragma unroll
        for (int off = 1; off < 64; off <<= 1) {
            int t = __shfl_up(incl, off);
            if (lane >= off) incl += t;
        }
        if (tid == 63) htot = incl;
    }
    __syncthreads();
    if (tid < 128) {
        const int excl = incl - v + ((tid >= 64) ? htot : 0);
        lc[tid] = gbase + excl;
        const int node = b * 128 + tid;
        if (node <= N_NODES) row_start[node] = gbase + excl;
    }
    __syncthreads();
    for (int i = gbase + tid; i < gend; i += 256) {
        const unsigned int p = packed[i];
        const int pos = atomicAdd(&lc[(p >> 16) & 127], 1);
        ssrc[pos] = (unsigned short)(p & 0xffffu);
    }
}

// 32 lanes per node (lane owns 4 features via ushort4), 2 nodes per wave,
// unroll 4 -> 8 row-gathers in flight per wave.
__global__ __launch_bounds__(256) void aggregate_mean_bf16(
    const unsigned short* __restrict__ featb, const int* __restrict__ row_start,
    const unsigned short* __restrict__ ssrc, unsigned short* __restrict__ aggb) {
    const int node = blockIdx.x * 8 + (threadIdx.x >> 5);
    const int l = threadIdx.x & 31;
    if (node >= N_NODES) return;
    const int beg = row_start[node], end = row_start[node + 1];
    float acc[4][4];
#pragma unroll
    for (int u = 0; u < 4; ++u)
#pragma unroll
        for (int f = 0; f < 4; ++f) acc[u][f] = 0.f;

    int j = beg;
    for (; j + 3 < end; j += 4) {
#pragma unroll
        for (int u = 0; u < 4; ++u) {
            const int s = ssrc[j + u];
            const ushort4 v = *reinterpret_cast<const ushort4*>(&featb[(size_t)s * HIDDEN + 4 * l]);
            acc[u][0] += bf2f(v.x); acc[u][1] += bf2f(v.y);
            acc[u][2] += bf2f(v.z); acc[u][3] += bf2f(v.w);
        }
    }
    for (; j < end; ++j) {
        const int s = ssrc[j];
        const ushort4 v = *reinterpret_cast<const ushort4*>(&featb[(size_t)s * HIDDEN + 4 * l]);
        acc[0][0] += bf2f(v.x); acc[0][1] += bf2f(v.y);
        acc[0][2] += bf2f(v.z); acc[0][3] += bf2f(v.w);
    }
    const int d = end - beg;
    const float inv = d ? 1.0f / (float)d : 0.0f;
    ushort4 o;
    o.x = f2bf((acc[0][0] + acc[1][0] + acc[2][0] + acc[3][0]) * inv);
    o.y = f2bf((acc[0][1] + acc[1][1] + acc[2][1] + acc[3][1]) * inv);
    o.z = f2bf((acc[0][2] + acc[1][2] + acc[2][2] + acc[3][2]) * inv);
    o.w = f2bf((acc[0][3] + acc[1][3] + acc[2][3] + acc[3][3]) * inv);
    *reinterpret_cast<ushort4*>(&aggb[(size_t)node * HIDDEN + 4 * l]) = o;
}

// out[n][t] = relu?( sum_k aggb[n][k]*Wl[t][k] + xb[n][k]*Wr[t][k] + b[t] )
// 4 waves/block (2M x 2N), 64-row x 128-col tile, K=256 in 8 steps of 32.
// Layer 1 (WRITE_BF16_RELU=1) writes bf16 IN-PLACE over xb: each block reads
// only its own 64 rows (k-loop) before its epilogue stores -> no hazard.
template <int WRITE_BF16_RELU>
__global__ __launch_bounds__(256) void mfma_linear(
    const unsigned short* aggb, const unsigned short* xb,
    const unsigned short* __restrict__ Wp, const float* __restrict__ bias,
    unsigned short* out_b, float* out_f) {
    const int lane = threadIdx.x & 63;
    const int wave = threadIdx.x >> 6;
    const int wm = wave >> 1, wn = wave & 1;
    const int rowbase = blockIdx.x * 64 + wm * 32;
    const int colbase = wn * 64;
    const int l15 = lane & 15, l4 = lane >> 4;

    f32x4 acc[2][4];
#pragma unroll
    for (int m = 0; m < 2; ++m)
#pragma unroll
        for (int nf = 0; nf < 4; ++nf) acc[m][nf] = (f32x4){0.f, 0.f, 0.f, 0.f};

#pragma unroll
    for (int ks = 0; ks < 8; ++ks) {
        const unsigned short* Asrc = (ks < 4) ? aggb : xb;
        const int koff = (ks & 3) * 32 + l4 * 8;
        short8 a[2];
#pragma unroll
        for (int m = 0; m < 2; ++m) {
            int row = rowbase + m * 16 + l15;
            if (row >= N_NODES) row = N_NODES - 1;
            a[m] = *reinterpret_cast<const short8*>(&Asrc[(size_t)row * HIDDEN + koff]);
        }
#pragma unroll
        for (int nf = 0; nf < 4; ++nf) {
            const int nfg = (colbase >> 4) + nf;
            short8 b = *reinterpret_cast<const short8*>(&Wp[(((size_t)ks * 8 + nfg) * 64 + lane) * 8]);
            acc[0][nf] = __builtin_amdgcn_mfma_f32_16x16x32_bf16(a[0], b, acc[0][nf], 0, 0, 0);
            acc[1][nf] = __builtin_amdgcn_mfma_f32_16x16x32_bf16(a[1], b, acc[1][nf], 0, 0, 0);
        }
    }

#pragma unroll
    for (int nf = 0; nf < 4; ++nf) {
        const int col = colbase + nf * 16 + l15;
        const float bv = bias[col];
#pragma unroll
        for (int m = 0; m < 2; ++m) {
#pragma unroll
            for (int r = 0; r < 4; ++r) {
                const int row = rowbase + m * 16 + l4 * 4 + r;
                if (row < N_NODES) {
                    float v = acc[m][nf][r] + bv;
                    if (WRITE_BF16_RELU) {
                        v = fmaxf(v, 0.0f);
                        out_b[(size_t)row * HIDDEN + col] = f2bf(v);
                    } else {
                        out_f[(size_t)row * HIDDEN + col] = v;
                    }
                }
            }
        }
    }
}

extern "C" void kernel_launch(void* const* d_in, const int* in_sizes, int n_in,
                              void* d_out, int out_size, void* d_ws, size_t ws_size,
                              hipStream_t stream) {
    const float* x   = (const float*)d_in[0];
    const int*   ei  = (const int*)d_in[1];
    const float* W1l = (const float*)d_in[2];
    const float* b1  = (const float*)d_in[3];
    const float* W1r = (const float*)d_in[4];
    const float* W2l = (const float*)d_in[5];
    const float* b2  = (const float*)d_in[6];
    const float* W2r = (const float*)d_in[7];

    const int E = in_sizes[1] / 2;
    const int* src = ei;
    const int* dst = ei + E;

    // ---- workspace layout (all sections 16B aligned) ----
    int* iws        = (int*)d_ws;
    int* bcnt       = iws;                       // @0    391 (pad 400)
    int* boff       = iws + 400;                 // @400  392 (pad 400)
    int* bcur       = iws + 800;                 // @800  391 (pad 400)
    int* row_start  = iws + 1200;                // @1200 50001 (pad 50004)
    unsigned int* packed = (unsigned int*)(iws + 51204);       // E u32
    unsigned short* ssrc = (unsigned short*)(iws + 51204 + E); // E u16 (E%8==0 keeps align)
    unsigned short* xb   = ssrc + E;             // 6.4M bf16 (h overwrites in-place)
    unsigned short* aggb = xb + (size_t)N_NODES * HIDDEN;      // 6.4M bf16
    unsigned short* Wp1  = aggb + (size_t)N_NODES * HIDDEN;    // 32768 bf16
    unsigned short* Wp2  = Wp1 + 256 * HIDDEN;                 // 32768 bf16

    hipMemsetAsync(bcnt, 0, NBUCK * sizeof(int), stream);

    pack_w<<<128, 256, 0, stream>>>(W1l, W1r, Wp1);
    pack_w<<<128, 256, 0, stream>>>(W2l, W2r, Wp2);
    cast_bf16<<<(N_NODES * HIDDEN / 4 + 255) / 256, 256, 0, stream>>>(x, xb, N_NODES * HIDDEN / 4);

    // ---- CSR build (shared by both layers) ----
    bucket_hist<<<196, 1024, 0, stream>>>(dst, E, bcnt);
    scan_buckets<<<1, 512, 0, stream>>>(bcnt, boff, bcur);
    partition_edges<<<(E + PCHUNK - 1) / PCHUNK, 1024, 0, stream>>>(src, dst, E, bcur, packed);
    build_rows<<<NBUCK, 256, 0, stream>>>(packed, boff, row_start, ssrc);

    const int aggGrid = (N_NODES + 7) / 8;
    const int linGrid = (N_NODES + 63) / 64;

    // ---- layer 1 ----
    aggregate_mean_bf16<<<aggGrid, 256, 0, stream>>>(xb, row_start, ssrc, aggb);
    mfma_linear<1><<<linGrid, 256, 0, stream>>>(aggb, xb, Wp1, b1, xb, nullptr);

    // ---- layer 2 ----
    aggregate_mean_bf16<<<aggGrid, 256, 0, stream>>>(xb, row_start, ssrc, aggb);
    mfma_linear<0><<<linGrid, 256, 0, stream>>>(aggb, xb, Wp2, b2, nullptr, (float*)d_out);
}

// Round 7
// 152.488 us; speedup vs baseline: 2.8138x; 1.0393x over previous
//
#include <hip/hip_runtime.h>

#define N_NODES 50000
#define HIDDEN 128
#define NBUCK ((N_NODES + 127) >> 7)  // 391 coarse buckets of 128 dst nodes

typedef __attribute__((ext_vector_type(8))) short short8;
typedef __attribute__((ext_vector_type(4))) float f32x4;

__device__ __forceinline__ unsigned short f2bf(float f) {
    union { float f; unsigned int u; } a; a.f = f;
    unsigned int u = a.u;
    u += 0x7FFFu + ((u >> 16) & 1u);  // RNE
    return (unsigned short)(u >> 16);
}
__device__ __forceinline__ float bf2f(unsigned int bits16) {
    union { unsigned int u; float f; } a; a.u = bits16 << 16;
    return a.f;
}

// Pack BOTH layers' Wcat[256][128] (rows 0..127 = Wl^T, 128..255 = Wr^T) into
// MFMA-B fragment order, and zero bcnt (replaces the pathological 42us
// hipMemsetAsync fill dispatch seen in R6's profile).
// Wp[((ks*8+nf)*64+lane)*8+j] = Wcat[ks*32+(lane>>4)*8+j][nf*16+(lane&15)]
__global__ __launch_bounds__(256) void pack_both(
    const float* __restrict__ W1l, const float* __restrict__ W1r,
    const float* __restrict__ W2l, const float* __restrict__ W2r,
    unsigned short* __restrict__ Wp1, unsigned short* __restrict__ Wp2,
    int* __restrict__ bcnt) {
    int tid = blockIdx.x * blockDim.x + threadIdx.x;  // 65536
    if (tid < NBUCK) bcnt[tid] = 0;
    const int which = tid >> 15;                      // 0 -> layer1, 1 -> layer2
    const int t2 = tid & 32767;
    int j = t2 & 7, lane = (t2 >> 3) & 63, nf = (t2 >> 9) & 7, ks = t2 >> 12;
    int k = ks * 32 + ((lane >> 4) * 8) + j;
    int t = nf * 16 + (lane & 15);
    const float* Wl = which ? W2l : W1l;
    const float* Wr = which ? W2r : W1r;
    float v = (k < 128) ? Wl[t * 128 + k] : Wr[t * 128 + (k - 128)];
    (which ? Wp2 : Wp1)[t2] = f2bf(v);
}

__global__ void cast_bf16(const float* __restrict__ x, unsigned short* __restrict__ xb, int n4) {
    int i = blockIdx.x * blockDim.x + threadIdx.x;
    if (i >= n4) return;
    float4 v = reinterpret_cast<const float4*>(x)[i];
    ushort4 o = make_ushort4(f2bf(v.x), f2bf(v.y), f2bf(v.z), f2bf(v.w));
    reinterpret_cast<ushort4*>(xb)[i] = o;
}

// ---- CSR build, two-level counting sort ----

// Coarse histogram: LDS per-block hist, then one global add per (block,bucket).
__global__ __launch_bounds__(1024) void bucket_hist(const int* __restrict__ dst, int E,
                                                    int* __restrict__ bcnt) {
    __shared__ int h[NBUCK];
    for (int i = threadIdx.x; i < NBUCK; i += 1024) h[i] = 0;
    __syncthreads();
    for (int e = blockIdx.x * 1024 + threadIdx.x; e < E; e += gridDim.x * 1024)
        atomicAdd(&h[dst[e] >> 7], 1);
    __syncthreads();
    for (int i = threadIdx.x; i < NBUCK; i += 1024)
        if (h[i]) atomicAdd(&bcnt[i], h[i]);
}

// Exclusive scan of 391 bucket counts (single block); writes boff[0..NBUCK] and bcur.
__global__ __launch_bounds__(512) void scan_buckets(const int* __restrict__ bcnt,
                                                    int* __restrict__ boff,
                                                    int* __restrict__ bcur) {
    __shared__ int ws[8];
    const int tid = threadIdx.x, lane = tid & 63, wid = tid >> 6;
    const int v = (tid < NBUCK) ? bcnt[tid] : 0;
    int incl = v;
#pragma unroll
    for (int off = 1; off < 64; off <<= 1) {
        int t = __shfl_up(incl, off);
        if (lane >= off) incl += t;
    }
    if (lane == 63) ws[wid] = incl;
    __syncthreads();
    if (wid == 0) {
        int wv = (lane < 8) ? ws[lane] : 0;
        int wincl = wv;
#pragma unroll
        for (int off = 1; off < 8; off <<= 1) {
            int t = __shfl_up(wincl, off);
            if (lane >= off) wincl += t;
        }
        if (lane < 8) ws[lane] = wincl - wv;
    }
    __syncthreads();
    const int excl = ws[wid] + incl - v;
    if (tid < NBUCK) { boff[tid] = excl; bcur[tid] = excl; }
    if (tid == NBUCK - 1) boff[NBUCK] = excl + v;
}

// Block-aggregated partition: each block reserves per-bucket ranges with ONE
// global atomic per (block,bucket), then scatters via LDS cursors.
#define PCHUNK 4096  // edges per block (1024 threads x 4)
__global__ __launch_bounds__(1024) void partition_edges(
    const int* __restrict__ src, const int* __restrict__ dst, int E,
    int* __restrict__ bcur, unsigned int* __restrict__ packed) {
    __shared__ int h[NBUCK];     // local hist, then local cursor
    __shared__ int base[NBUCK];  // reserved global base per bucket
    const int tid = threadIdx.x;
    const int c0 = blockIdx.x * PCHUNK;
    for (int i = tid; i < NBUCK; i += 1024) h[i] = 0;
    __syncthreads();

    unsigned int val[4];
    int bk[4];
#pragma unroll
    for (int u = 0; u < 4; ++u) {
        const int e = c0 + u * 1024 + tid;
        if (e < E) {
            const int d = dst[e];
            val[u] = ((unsigned int)d << 16) | (unsigned int)src[e];
            bk[u] = d >> 7;
            atomicAdd(&h[bk[u]], 1);
        } else {
            bk[u] = -1;
        }
    }
    __syncthreads();
    for (int i = tid; i < NBUCK; i += 1024) {
        base[i] = h[i] ? atomicAdd(&bcur[i], h[i]) : 0;
        h[i] = 0;  // reuse as local cursor
    }
    __syncthreads();
#pragma unroll
    for (int u = 0; u < 4; ++u) {
        if (bk[u] >= 0) {
            const int pos = base[bk[u]] + atomicAdd(&h[bk[u]], 1);
            packed[pos] = val[u];
        }
    }
}

// One block per bucket: LDS 128-bin hist + scan -> row_start; LDS-cursor scatter
// of u16 srcs into the bucket's contiguous ~4KB output region.
__global__ __launch_bounds__(256) void build_rows(const unsigned int* __restrict__ packed,
                                                  const int* __restrict__ boff,
                                                  int* __restrict__ row_start,
                                                  unsigned short* __restrict__ ssrc) {
    __shared__ int lh[128];
    __shared__ int lc[128];
    __shared__ int htot;
    const int b = blockIdx.x;
    const int gbase = boff[b], gend = boff[b + 1];
    const int tid = threadIdx.x;
    if (tid < 128) lh[tid] = 0;
    __syncthreads();
    for (int i = gbase + tid; i < gend; i += 256)
        atomicAdd(&lh[(packed[i] >> 16) & 127], 1);
    __syncthreads();
    int v = 0, incl = 0;
    if (tid < 128) {
        const int lane = tid & 63;
        v = lh[tid];
        incl = v;
#pragma unroll
        for (int off = 1; off < 64; off <<= 1) {
            int t = __shfl_up(incl, off);
            if (lane >= off) incl += t;
        }
        if (tid == 63) htot = incl;
    }
    __syncthreads();
    if (tid < 128) {
        const int excl = incl - v + ((tid >= 64) ? htot : 0);
        lc[tid] = gbase + excl;
        const int node = b * 128 + tid;
        if (node <= N_NODES) row_start[node] = gbase + excl;
    }
    __syncthreads();
    for (int i = gbase + tid; i < gend; i += 256) {
        const unsigned int p = packed[i];
        const int pos = atomicAdd(&lc[(p >> 16) & 127], 1);
        ssrc[pos] = (unsigned short)(p & 0xffffu);
    }
}

// 32 lanes per node (lane owns 4 features via ushort4), 2 nodes per wave,
// unroll 4 -> 8 row-gathers in flight per wave.
__global__ __launch_bounds__(256) void aggregate_mean_bf16(
    const unsigned short* __restrict__ featb, const int* __restrict__ row_start,
    const unsigned short* __restrict__ ssrc, unsigned short* __restrict__ aggb) {
    const int node = blockIdx.x * 8 + (threadIdx.x >> 5);
    const int l = threadIdx.x & 31;
    if (node >= N_NODES) return;
    const int beg = row_start[node], end = row_start[node + 1];
    float acc[4][4];
#pragma unroll
    for (int u = 0; u < 4; ++u)
#pragma unroll
        for (int f = 0; f < 4; ++f) acc[u][f] = 0.f;

    int j = beg;
    for (; j + 3 < end; j += 4) {
#pragma unroll
        for (int u = 0; u < 4; ++u) {
            const int s = ssrc[j + u];
            const ushort4 v = *reinterpret_cast<const ushort4*>(&featb[(size_t)s * HIDDEN + 4 * l]);
            acc[u][0] += bf2f(v.x); acc[u][1] += bf2f(v.y);
            acc[u][2] += bf2f(v.z); acc[u][3] += bf2f(v.w);
        }
    }
    for (; j < end; ++j) {
        const int s = ssrc[j];
        const ushort4 v = *reinterpret_cast<const ushort4*>(&featb[(size_t)s * HIDDEN + 4 * l]);
        acc[0][0] += bf2f(v.x); acc[0][1] += bf2f(v.y);
        acc[0][2] += bf2f(v.z); acc[0][3] += bf2f(v.w);
    }
    const int d = end - beg;
    const float inv = d ? 1.0f / (float)d : 0.0f;
    ushort4 o;
    o.x = f2bf((acc[0][0] + acc[1][0] + acc[2][0] + acc[3][0]) * inv);
    o.y = f2bf((acc[0][1] + acc[1][1] + acc[2][1] + acc[3][1]) * inv);
    o.z = f2bf((acc[0][2] + acc[1][2] + acc[2][2] + acc[3][2]) * inv);
    o.w = f2bf((acc[0][3] + acc[1][3] + acc[2][3] + acc[3][3]) * inv);
    *reinterpret_cast<ushort4*>(&aggb[(size_t)node * HIDDEN + 4 * l]) = o;
}

// out[n][t] = relu?( sum_k aggb[n][k]*Wl[t][k] + xb[n][k]*Wr[t][k] + b[t] )
// 4 waves/block (2M x 2N), 64-row x 128-col tile, K=256 in 8 steps of 32.
// Layer 1 (WRITE_BF16_RELU=1) writes bf16 IN-PLACE over xb: each block reads
// only its own 64 rows (k-loop) before its epilogue stores -> no hazard.
template <int WRITE_BF16_RELU>
__global__ __launch_bounds__(256) void mfma_linear(
    const unsigned short* aggb, const unsigned short* xb,
    const unsigned short* __restrict__ Wp, const float* __restrict__ bias,
    unsigned short* out_b, float* out_f) {
    const int lane = threadIdx.x & 63;
    const int wave = threadIdx.x >> 6;
    const int wm = wave >> 1, wn = wave & 1;
    const int rowbase = blockIdx.x * 64 + wm * 32;
    const int colbase = wn * 64;
    const int l15 = lane & 15, l4 = lane >> 4;

    f32x4 acc[2][4];
#pragma unroll
    for (int m = 0; m < 2; ++m)
#pragma unroll
        for (int nf = 0; nf < 4; ++nf) acc[m][nf] = (f32x4){0.f, 0.f, 0.f, 0.f};

#pragma unroll
    for (int ks = 0; ks < 8; ++ks) {
        const unsigned short* Asrc = (ks < 4) ? aggb : xb;
        const int koff = (ks & 3) * 32 + l4 * 8;
        short8 a[2];
#pragma unroll
        for (int m = 0; m < 2; ++m) {
            int row = rowbase + m * 16 + l15;
            if (row >= N_NODES) row = N_NODES - 1;
            a[m] = *reinterpret_cast<const short8*>(&Asrc[(size_t)row * HIDDEN + koff]);
        }
#pragma unroll
        for (int nf = 0; nf < 4; ++nf) {
            const int nfg = (colbase >> 4) + nf;
            short8 b = *reinterpret_cast<const short8*>(&Wp[(((size_t)ks * 8 + nfg) * 64 + lane) * 8]);
            acc[0][nf] = __builtin_amdgcn_mfma_f32_16x16x32_bf16(a[0], b, acc[0][nf], 0, 0, 0);
            acc[1][nf] = __builtin_amdgcn_mfma_f32_16x16x32_bf16(a[1], b, acc[1][nf], 0, 0, 0);
        }
    }

#pragma unroll
    for (int nf = 0; nf < 4; ++nf) {
        const int col = colbase + nf * 16 + l15;
        const float bv = bias[col];
#pragma unroll
        for (int m = 0; m < 2; ++m) {
#pragma unroll
            for (int r = 0; r < 4; ++r) {
                const int row = rowbase + m * 16 + l4 * 4 + r;
                if (row < N_NODES) {
                    float v = acc[m][nf][r] + bv;
                    if (WRITE_BF16_RELU) {
                        v = fmaxf(v, 0.0f);
                        out_b[(size_t)row * HIDDEN + col] = f2bf(v);
                    } else {
                        out_f[(size_t)row * HIDDEN + col] = v;
                    }
                }
            }
        }
    }
}

extern "C" void kernel_launch(void* const* d_in, const int* in_sizes, int n_in,
                              void* d_out, int out_size, void* d_ws, size_t ws_size,
                              hipStream_t stream) {
    const float* x   = (const float*)d_in[0];
    const int*   ei  = (const int*)d_in[1];
    const float* W1l = (const float*)d_in[2];
    const float* b1  = (const float*)d_in[3];
    const float* W1r = (const float*)d_in[4];
    const float* W2l = (const float*)d_in[5];
    const float* b2  = (const float*)d_in[6];
    const float* W2r = (const float*)d_in[7];

    const int E = in_sizes[1] / 2;
    const int* src = ei;
    const int* dst = ei + E;

    // ---- workspace layout (all sections 16B aligned) ----
    int* iws        = (int*)d_ws;
    int* bcnt       = iws;                       // @0    391 (pad 400)
    int* boff       = iws + 400;                 // @400  392 (pad 400)
    int* bcur       = iws + 800;                 // @800  391 (pad 400)
    int* row_start  = iws + 1200;                // @1200 50001 (pad 50004)
    unsigned int* packed = (unsigned int*)(iws + 51204);       // E u32
    unsigned short* ssrc = (unsigned short*)(iws + 51204 + E); // E u16 (E%8==0 keeps align)
    unsigned short* xb   = ssrc + E;             // 6.4M bf16 (h overwrites in-place)
    unsigned short* aggb = xb + (size_t)N_NODES * HIDDEN;      // 6.4M bf16
    unsigned short* Wp1  = aggb + (size_t)N_NODES * HIDDEN;    // 32768 bf16
    unsigned short* Wp2  = Wp1 + 256 * HIDDEN;                 // 32768 bf16

    // pack both weight sets + zero bcnt (no hipMemsetAsync fill dispatch)
    pack_both<<<256, 256, 0, stream>>>(W1l, W1r, W2l, W2r, Wp1, Wp2, bcnt);
    cast_bf16<<<(N_NODES * HIDDEN / 4 + 255) / 256, 256, 0, stream>>>(x, xb, N_NODES * HIDDEN / 4);

    // ---- CSR build (shared by both layers) ----
    bucket_hist<<<196, 1024, 0, stream>>>(dst, E, bcnt);
    scan_buckets<<<1, 512, 0, stream>>>(bcnt, boff, bcur);
    partition_edges<<<(E + PCHUNK - 1) / PCHUNK, 1024, 0, stream>>>(src, dst, E, bcur, packed);
    build_rows<<<NBUCK, 256, 0, stream>>>(packed, boff, row_start, ssrc);

    const int aggGrid = (N_NODES + 7) / 8;
    const int linGrid = (N_NODES + 63) / 64;

    // ---- layer 1 ----
    aggregate_mean_bf16<<<aggGrid, 256, 0, stream>>>(xb, row_start, ssrc, aggb);
    mfma_linear<1><<<linGrid, 256, 0, stream>>>(aggb, xb, Wp1, b1, xb, nullptr);

    // ---- layer 2 ----
    aggregate_mean_bf16<<<aggGrid, 256, 0, stream>>>(xb, row_start, ssrc, aggb);
    mfma_linear<0><<<linGrid, 256, 0, stream>>>(aggb, xb, Wp2, b2, nullptr, (float*)d_out);
}